// Round 8
// baseline (1111.102 us; speedup 1.0000x reference)
//
#include <hip/hip_runtime.h>
#include <hip/hip_bf16.h>
#include <cstdint>

// Conformer block, MI355X gfx950. f32 inputs, **f32 output**, bf16 MFMA internals.
// B=8 N=1024 D=512 H=8 DH=64 FF=2048 CI=1024 K=31 MPE=512.
// Round 8: round-4 MFMA pipeline + final LN writes FLOAT32 (the round 0-7 bug).

using bf16_t = __hip_bfloat16;
typedef __bf16 bf16x8 __attribute__((ext_vector_type(8)));
typedef float floatx4 __attribute__((ext_vector_type(4)));

struct alignas(16) hbf8 { bf16_t h[8]; };
struct alignas(8)  hbf4 { bf16_t h[4]; };

__device__ __forceinline__ float  b2f(bf16_t h) { return __bfloat162float(h); }
__device__ __forceinline__ bf16_t f2b(float f)  { return __float2bfloat16(f); }
__device__ __forceinline__ float  sig_(float x) { return 1.f / (1.f + __expf(-x)); }

// ---------------------------------------------------------------- GEMM (MFMA)
// C[M,N] = A[M,K] @ Bt[N,K]^T   (bf16 operands, k-contiguous, f32 accum)
// EPI 0: C_bf16 = alpha*acc + bias        (bias f32, optional)
// EPI 1: C_bf16 = swish(acc + bias)
// EPI 2: resid_f32[i*ldc+j] += beta*(acc + bias)
// EPI 3: C_bf16 = acc + qr[(i*8+zh)*ldqr + clip(i-j,+-512)+512]
struct GemmArgs {
  const bf16_t* A; const bf16_t* Bt; const float* bias; const bf16_t* qr;
  bf16_t* C; float* resid;
  int K, lda, ldb, ldc, ldqr;
  long sAh, sBh, sCh;   // per-z (blockIdx.z) strides in elements
  float alpha, beta;
};

template <int BM, int BN, int WR, int WC, int EPI>
__global__ __launch_bounds__(256) void gemm_bt(GemmArgs g) {
  constexpr int FM = BM / (WR * 16);
  constexpr int FN = BN / (WC * 16);
  constexpr int IA = (BM * 4) / 256;
  constexpr int IB = (BN * 4) / 256;
  __shared__ __align__(16) bf16_t As[BM * 32];
  __shared__ __align__(16) bf16_t Bs[BN * 32];
  const int tid = threadIdx.x;
  const int lane = tid & 63, w = tid >> 6;
  const int bm0 = blockIdx.y * BM, bn0 = blockIdx.x * BN;
  const int zh = blockIdx.z;
  const bf16_t* Ab = g.A + (long)zh * g.sAh;
  const bf16_t* Bb = g.Bt + (long)zh * g.sBh;
  const int wm0 = (w / WC) * (FM * 16);
  const int wn0 = (w % WC) * (FN * 16);
  const int lrow = lane & 15, lq = lane >> 4;

  floatx4 acc[FM][FN] = {};

  for (int k0 = 0; k0 < g.K; k0 += 32) {
    bf16x8 va[IA], vb[IB];
#pragma unroll
    for (int i = 0; i < IA; ++i) {
      int c = i * 256 + tid;
      int m = c >> 2, kk = (c & 3) * 8;
      va[i] = *(const bf16x8*)(Ab + (long)(bm0 + m) * g.lda + (k0 + kk));
    }
#pragma unroll
    for (int i = 0; i < IB; ++i) {
      int c = i * 256 + tid;
      int n = bn0 + (c >> 2), kk = (c & 3) * 8;
      vb[i] = *(const bf16x8*)(Bb + (long)n * g.ldb + (k0 + kk));
    }
#pragma unroll
    for (int i = 0; i < IA; ++i) { int c = i * 256 + tid; *(bf16x8*)(As + c * 8) = va[i]; }
#pragma unroll
    for (int i = 0; i < IB; ++i) { int c = i * 256 + tid; *(bf16x8*)(Bs + c * 8) = vb[i]; }
    __syncthreads();
    bf16x8 af[FM], bfr[FN];
#pragma unroll
    for (int fm = 0; fm < FM; ++fm)
      af[fm] = *(const bf16x8*)(As + (wm0 + fm * 16 + lrow) * 32 + lq * 8);
#pragma unroll
    for (int fn = 0; fn < FN; ++fn)
      bfr[fn] = *(const bf16x8*)(Bs + (wn0 + fn * 16 + lrow) * 32 + lq * 8);
#pragma unroll
    for (int fm = 0; fm < FM; ++fm)
#pragma unroll
      for (int fn = 0; fn < FN; ++fn)
        acc[fm][fn] = __builtin_amdgcn_mfma_f32_16x16x32_bf16(af[fm], bfr[fn], acc[fm][fn], 0, 0, 0);
    __syncthreads();
  }

  const int bi = bm0 + wm0 + lq * 4;    // + fm*16 + r
  const int bj = bn0 + wn0 + lrow;      // + fn*16
  if constexpr (EPI == 2) {
    float* R = g.resid;
#pragma unroll
    for (int fm = 0; fm < FM; ++fm)
#pragma unroll
      for (int fn = 0; fn < FN; ++fn) {
        int j = bj + fn * 16;
        float bv = g.bias ? g.bias[j] : 0.f;
#pragma unroll
        for (int r = 0; r < 4; ++r) {
          long i = bi + fm * 16 + r;
          R[i * g.ldc + j] += g.beta * (acc[fm][fn][r] + bv);
        }
      }
  } else {
    bf16_t* C = g.C + (long)zh * g.sCh;
#pragma unroll
    for (int fm = 0; fm < FM; ++fm)
#pragma unroll
      for (int fn = 0; fn < FN; ++fn) {
        int j = bj + fn * 16;
        float bv = (EPI != 3 && g.bias) ? g.bias[j] : 0.f;
#pragma unroll
        for (int r = 0; r < 4; ++r) {
          int i = bi + fm * 16 + r;
          float v = acc[fm][fn][r];
          if constexpr (EPI == 0) v = g.alpha * v + bv;
          if constexpr (EPI == 1) { v += bv; v = v * sig_(v); }
          if constexpr (EPI == 3) {
            int t = i - j; t = t < -512 ? -512 : (t > 512 ? 512 : t);
            v += b2f(g.qr[(long)(i * 8 + zh) * g.ldqr + (t + 512)]);
          }
          C[(long)i * g.ldc + j] = f2b(v);
        }
      }
  }
}

// ---------------------------------------------------------------- glue kernels
__global__ __launch_bounds__(256) void diag_kernel(float* __restrict__ out, long n, float v) {
  long i = (long)blockIdx.x * 256 + threadIdx.x;
  if (i < n) out[i] = v;
}

__global__ __launch_bounds__(256) void copy_kernel(const float* __restrict__ x, float* __restrict__ X) {
  long idx = ((long)blockIdx.x * 256 + threadIdx.x) * 4;
  *(float4*)(X + idx) = *(const float4*)(x + idx);
}

// pad rel [1025,64] f32 -> RELP [1152,64] bf16 (zero tail)
__global__ __launch_bounds__(256) void relpad_kernel(const float* __restrict__ rel, bf16_t* __restrict__ RELP) {
  int i = blockIdx.x * 256 + threadIdx.x;   // 1152*64 = 73728
  if (i < 73728) {
    int r = i >> 6, c = i & 63;
    RELP[i] = (r < 1025) ? f2b(rel[r * 64 + c]) : f2b(0.f);
  }
}

// one block per row of 512; out = (x-mean)*rsqrt(var+1e-5)*g + b
template <bool F32OUT>
__global__ __launch_bounds__(256) void ln_kernel(const float* __restrict__ X, const float* __restrict__ gam,
                                                 const float* __restrict__ bet, void* __restrict__ outv) {
  int row = blockIdx.x, tid = threadIdx.x;
  const float* x = X + (long)row * 512;
  float a = x[tid], b = x[tid + 256];
  float s = a + b, q = a * a + b * b;
  for (int off = 32; off; off >>= 1) { s += __shfl_down(s, off); q += __shfl_down(q, off); }
  __shared__ float red[8];
  int w = tid >> 6;
  if ((tid & 63) == 0) { red[w] = s; red[w + 4] = q; }
  __syncthreads();
  float ts = red[0] + red[1] + red[2] + red[3];
  float tq = red[4] + red[5] + red[6] + red[7];
  float mean = ts * (1.f / 512.f);
  float var = tq * (1.f / 512.f) - mean * mean;
  float rs = rsqrtf(var + 1e-5f);
  float o0 = (a - mean) * rs * gam[tid]       + bet[tid];
  float o1 = (b - mean) * rs * gam[tid + 256] + bet[tid + 256];
  if constexpr (F32OUT) {
    float* out = (float*)outv;
    out[(long)row * 512 + tid]       = o0;
    out[(long)row * 512 + tid + 256] = o1;
  } else {
    bf16_t* out = (bf16_t*)outv;
    out[(long)row * 512 + tid]       = f2b(o0);
    out[(long)row * 512 + tid + 256] = f2b(o1);
  }
}

// 32x32 LDS tile transpose + cast: out_bf16[C,R] = in_f32[R,C]^T
__global__ __launch_bounds__(256) void transpose_kernel(const float* __restrict__ in, bf16_t* __restrict__ out,
                                                        int R, int C) {
  __shared__ float t[32][33];
  int c0 = blockIdx.x * 32, r0 = blockIdx.y * 32;
  int tx = threadIdx.x & 31, ty = threadIdx.x >> 5;
#pragma unroll
  for (int i = 0; i < 4; ++i)
    t[ty + i * 8][tx] = in[(long)(r0 + ty + i * 8) * C + c0 + tx];
  __syncthreads();
#pragma unroll
  for (int i = 0; i < 4; ++i)
    out[(long)(c0 + ty + i * 8) * R + r0 + tx] = f2b(t[tx][ty + i * 8]);
}

// VT[z=b*8+h][d][j] = KV[(b*1024+j)*1024 + 512 + h*64 + d]
__global__ __launch_bounds__(256) void vt_kernel(const bf16_t* __restrict__ KV, bf16_t* __restrict__ VT) {
  int jb = blockIdx.x, z = blockIdx.y;
  int b = z >> 3, h = z & 7;
  const bf16_t* src = KV + (long)b * 1024 * 1024 + 512 + h * 64;
  bf16_t* dst = VT + (long)z * 65536;
  __shared__ bf16_t t[64][65];
  int tid = threadIdx.x;
#pragma unroll
  for (int i = 0; i < 16; ++i) {
    int l = i * 256 + tid;
    int j = l >> 6, d = l & 63;
    t[d][j] = src[(long)(jb * 64 + j) * 1024 + d];
  }
  __syncthreads();
#pragma unroll
  for (int i = 0; i < 16; ++i) {
    int l = i * 256 + tid;
    int d = l >> 6, j = l & 63;
    dst[(long)d * 1024 + jb * 64 + j] = t[d][j];
  }
}

// row softmax over 1024, in place, bf16<->f32
__global__ __launch_bounds__(256) void softmax_kernel(bf16_t* __restrict__ S) {
  long row = blockIdx.x;
  bf16_t* p = S + row * 1024;
  int tid = threadIdx.x, w = tid >> 6;
  hbf4 d = *(const hbf4*)(p + tid * 4);
  float v0 = b2f(d.h[0]), v1 = b2f(d.h[1]), v2 = b2f(d.h[2]), v3 = b2f(d.h[3]);
  float m = fmaxf(fmaxf(v0, v1), fmaxf(v2, v3));
  for (int off = 32; off; off >>= 1) m = fmaxf(m, __shfl_down(m, off));
  __shared__ float r1[4], r2[4];
  if ((tid & 63) == 0) r1[w] = m;
  __syncthreads();
  m = fmaxf(fmaxf(r1[0], r1[1]), fmaxf(r1[2], r1[3]));
  float e0 = __expf(v0 - m), e1 = __expf(v1 - m), e2 = __expf(v2 - m), e3 = __expf(v3 - m);
  float s = e0 + e1 + e2 + e3;
  for (int off = 32; off; off >>= 1) s += __shfl_down(s, off);
  if ((tid & 63) == 0) r2[w] = s;
  __syncthreads();
  float inv = 1.f / (r2[0] + r2[1] + r2[2] + r2[3]);
  hbf4 o; o.h[0] = f2b(e0 * inv); o.h[1] = f2b(e1 * inv); o.h[2] = f2b(e2 * inv); o.h[3] = f2b(e3 * inv);
  *(hbf4*)(p + tid * 4) = o;
}

// GLU: out[r,c] = P[r,c] * sigmoid(P[r,c+1024]),  P rows of 2048
__global__ __launch_bounds__(256) void glu_kernel(const bf16_t* __restrict__ P, bf16_t* __restrict__ out) {
  long idx = ((long)blockIdx.x * 256 + threadIdx.x) * 8;
  long r = idx >> 10;
  int c = (int)(idx & 1023);
  hbf8 a = *(const hbf8*)(P + r * 2048 + c);
  hbf8 g = *(const hbf8*)(P + r * 2048 + 1024 + c);
  hbf8 o;
#pragma unroll
  for (int i = 0; i < 8; ++i) o.h[i] = f2b(b2f(a.h[i]) * sig_(b2f(g.h[i])));
  *(hbf8*)(out + idx) = o;
}

// depthwise conv (K=31, pad 15/15) + BN(eval) + swish, [B,N,CI] layout; f32 params
__global__ __launch_bounds__(256) void dwconv_kernel(const bf16_t* __restrict__ G, const float* __restrict__ dw,
    const float* __restrict__ db, const float* __restrict__ bng, const float* __restrict__ bnb,
    const float* __restrict__ bnm, const float* __restrict__ bnv, bf16_t* __restrict__ out) {
  int n0 = blockIdx.x * 32, c0 = blockIdx.y * 64, b = blockIdx.z;
  __shared__ bf16_t t[62][64];
  __shared__ float dws[31][64];
  int tid = threadIdx.x;
  const bf16_t* src = G + (long)b * 1024 * 1024 + c0;
#pragma unroll
  for (int i = 0; i < 16; ++i) {
    int l = i * 256 + tid;
    if (l < 3968) {
      int rr = l >> 6, c = l & 63;
      int n = n0 - 15 + rr;
      t[rr][c] = (n >= 0 && n < 1024) ? src[(long)n * 1024 + c] : f2b(0.f);
    }
  }
#pragma unroll
  for (int i = 0; i < 8; ++i) {
    int l = i * 256 + tid;
    if (l < 1984) {
      int k = l >> 6, c = l & 63;
      dws[k][c] = dw[(long)(c0 + c) * 31 + k];
    }
  }
  __syncthreads();
  int c = tid & 63, nl = tid >> 6;
  float rs = rsqrtf(bnv[c0 + c] + 1e-5f);
  float sc = rs * bng[c0 + c];
  float ab = (db[c0 + c] - bnm[c0 + c]) * sc + bnb[c0 + c];
#pragma unroll
  for (int j = 0; j < 8; ++j) {
    int rr = nl * 8 + j;
    float s = 0.f;
#pragma unroll
    for (int k = 0; k < 31; ++k) s += b2f(t[rr + k][c]) * dws[k][c];
    float y = s * sc + ab;
    out[((long)b * 1024 + n0 + rr) * 1024 + c0 + c] = f2b(y * sig_(y));
  }
}

// ---------------------------------------------------------------- launch
extern "C" void kernel_launch(void* const* d_in, const int* in_sizes, int n_in,
                              void* d_out, int out_size, void* d_ws, size_t ws_size,
                              hipStream_t stream) {
  auto fail = [&](float code) {
    diag_kernel<<<(out_size + 255) / 256, 256, 0, stream>>>((float*)d_out, out_size, code);
  };
  if (n_in != 34)             { fail(70.f);  return; }
  if (in_sizes[0] != 4194304) { fail(80.f);  return; }

  const float* x     = (const float*)d_in[0];
  const float* f1_g  = (const float*)d_in[1];
  const float* f1_b  = (const float*)d_in[2];
  const float* f1_w1 = (const float*)d_in[3];
  const float* f1_b1 = (const float*)d_in[4];
  const float* f1_w2 = (const float*)d_in[5];
  const float* f1_b2 = (const float*)d_in[6];
  const float* a_g   = (const float*)d_in[7];
  const float* a_b   = (const float*)d_in[8];
  const float* wq    = (const float*)d_in[9];
  const float* wkv   = (const float*)d_in[10];
  const float* wo    = (const float*)d_in[11];
  const float* wo_b  = (const float*)d_in[12];
  const float* rel   = (const float*)d_in[13];
  const float* c_g   = (const float*)d_in[14];
  const float* c_b   = (const float*)d_in[15];
  const float* cw1   = (const float*)d_in[16];
  const float* cb1   = (const float*)d_in[17];
  const float* dwp   = (const float*)d_in[18];
  const float* dbp   = (const float*)d_in[19];
  const float* bn_g  = (const float*)d_in[20];
  const float* bn_b  = (const float*)d_in[21];
  const float* bn_m  = (const float*)d_in[22];
  const float* bn_v  = (const float*)d_in[23];
  const float* cw2   = (const float*)d_in[24];
  const float* cb2   = (const float*)d_in[25];
  const float* f2_g  = (const float*)d_in[26];
  const float* f2_b  = (const float*)d_in[27];
  const float* f2_w1 = (const float*)d_in[28];
  const float* f2_b1 = (const float*)d_in[29];
  const float* f2_w2 = (const float*)d_in[30];
  const float* f2_b2 = (const float*)d_in[31];
  const float* p_g   = (const float*)d_in[32];
  const float* p_b   = (const float*)d_in[33];

  // ---- workspace arena (~97 MB) ----
  // X   f32 residual   16,777,216
  // WT  transposed W   13,631,488 (bf16)
  // D   32 MB: attn {Q 8M, KV 16M, VT 8M} / conv {GLU 16M, DWO 16M}
  // E   36 MB: {MID 32M} / attn per-batch {QR 18.9M, S 16.8M, RELP 144K}
  char* ws = (char*)d_ws;
  const size_t OFF_X  = 0;
  const size_t OFF_WT = 16777216;
  const size_t OFF_D  = 30408704;
  const size_t OFF_E  = 63963136;
  const size_t NEED   = 101711872;
  if (ws_size < NEED) { fail(200.f); return; }

  float*  X   = (float*)(ws + OFF_X);
  bf16_t* WT  = (bf16_t*)(ws + OFF_WT);
  bf16_t* Q   = (bf16_t*)(ws + OFF_D);
  bf16_t* KV  = (bf16_t*)(ws + OFF_D + 8388608);
  bf16_t* VT  = (bf16_t*)(ws + OFF_D + 25165824);
  bf16_t* GLU = (bf16_t*)(ws + OFF_D);
  bf16_t* DWO = (bf16_t*)(ws + OFF_D + 16777216);
  bf16_t* MID = (bf16_t*)(ws + OFF_E);
  bf16_t* QR  = (bf16_t*)(ws + OFF_E);             // per-batch, overlays MID
  bf16_t* S   = (bf16_t*)(ws + OFF_E + 18874368);  // per-batch
  bf16_t* RELP= (bf16_t*)(ws + OFF_E + 35651584);  // padded rel [1152,64] bf16
  bf16_t* H   = (bf16_t*)d_out;                    // bf16 scratch in f32 out buf (16 MB)
  bf16_t* O   = (bf16_t*)d_out;                    // final f32 LN overwrites at end

  bf16_t* f1_w1t = WT;            bf16_t* f1_w2t = WT + 1048576;
  bf16_t* wqt    = WT + 2097152;  bf16_t* wkvt   = WT + 2359296;
  bf16_t* wot    = WT + 2883584;  bf16_t* cw1t   = WT + 3145728;
  bf16_t* cw2t   = WT + 4194304;  bf16_t* f2_w1t = WT + 4718592;
  bf16_t* f2_w2t = WT + 5767168;

  auto GA = [](const bf16_t* A, const bf16_t* Bt, const float* bias, bf16_t* C,
               float* resid, const bf16_t* qr, int K, int lda, int ldb, int ldc,
               float alpha, float beta) {
    GemmArgs g{}; g.A = A; g.Bt = Bt; g.bias = bias; g.qr = qr; g.C = C; g.resid = resid;
    g.K = K; g.lda = lda; g.ldb = ldb; g.ldc = ldc; g.ldqr = 1152;
    g.sAh = g.sBh = g.sCh = 0; g.alpha = alpha; g.beta = beta;
    return g;
  };
  auto T = [&](const float* in, bf16_t* out, int R, int C) {
    transpose_kernel<<<dim3(C / 32, R / 32), 256, 0, stream>>>(in, out, R, C);
  };

  copy_kernel<<<4096, 256, 0, stream>>>(x, X);
  relpad_kernel<<<288, 256, 0, stream>>>(rel, RELP);
  T(f1_w1, f1_w1t, 512, 2048);  T(f1_w2, f1_w2t, 2048, 512);
  T(wq, wqt, 512, 512);         T(wkv, wkvt, 512, 1024);
  T(wo, wot, 512, 512);         T(cw1, cw1t, 512, 2048);
  T(cw2, cw2t, 1024, 512);      T(f2_w1, f2_w1t, 512, 2048);
  T(f2_w2, f2_w2t, 2048, 512);

  // ---- FF1 half-step ----
  ln_kernel<false><<<8192, 256, 0, stream>>>(X, f1_g, f1_b, H);
  { GemmArgs g = GA(H, f1_w1t, f1_b1, MID, nullptr, nullptr, 512, 512, 512, 2048, 1.f, 0.f);
    gemm_bt<128, 128, 2, 2, 1><<<dim3(16, 64, 1), 256, 0, stream>>>(g); }
  { GemmArgs g = GA(MID, f1_w2t, f1_b2, nullptr, X, nullptr, 2048, 2048, 2048, 512, 1.f, 0.5f);
    gemm_bt<128, 128, 2, 2, 2><<<dim3(4, 64, 1), 256, 0, stream>>>(g); }

  // ---- attention ----
  ln_kernel<false><<<8192, 256, 0, stream>>>(X, a_g, a_b, H);
  { GemmArgs g = GA(H, wqt, nullptr, Q, nullptr, nullptr, 512, 512, 512, 512, 0.125f, 0.f);
    gemm_bt<128, 128, 2, 2, 0><<<dim3(4, 64, 1), 256, 0, stream>>>(g); }   // q (scale folded)
  { GemmArgs g = GA(H, wkvt, nullptr, KV, nullptr, nullptr, 512, 512, 512, 1024, 1.f, 0.f);
    gemm_bt<128, 128, 2, 2, 0><<<dim3(8, 64, 1), 256, 0, stream>>>(g); }   // k|v
  vt_kernel<<<dim3(16, 64), 256, 0, stream>>>(KV, VT);

  for (int b = 0; b < 8; ++b) {
    const bf16_t* Qb  = Q  + (long)b * 524288;
    const bf16_t* KVb = KV + (long)b * 1048576;
    { GemmArgs g = GA(Qb, RELP, nullptr, QR, nullptr, nullptr, 64, 64, 64, 1152, 1.f, 0.f);
      gemm_bt<128, 128, 2, 2, 0><<<dim3(9, 64, 1), 256, 0, stream>>>(g); }  // qr = q@rel^T
    { GemmArgs g = GA(Qb, KVb, nullptr, S, nullptr, QR, 64, 512, 1024, 1024, 1.f, 0.f);
      g.sAh = 64; g.sBh = 64; g.sCh = 1048576;
      gemm_bt<128, 128, 2, 2, 3><<<dim3(8, 8, 8), 256, 0, stream>>>(g); }   // S = qk^T + bias
    softmax_kernel<<<8192, 256, 0, stream>>>(S);
    { GemmArgs g = GA(S, VT + (long)b * 524288, nullptr, O + (long)b * 524288, nullptr, nullptr,
                      1024, 1024, 1024, 512, 1.f, 0.f);
      g.sAh = 1048576; g.sBh = 65536; g.sCh = 64;
      gemm_bt<128, 64, 4, 1, 0><<<dim3(1, 8, 8), 256, 0, stream>>>(g); }    // O = P@V
  }
  { GemmArgs g = GA(O, wot, wo_b, nullptr, X, nullptr, 512, 512, 512, 512, 1.f, 1.f);
    gemm_bt<128, 128, 2, 2, 2><<<dim3(4, 64, 1), 256, 0, stream>>>(g); }   // x += o@wo + b

  // ---- conv module ----
  ln_kernel<false><<<8192, 256, 0, stream>>>(X, c_g, c_b, H);
  { GemmArgs g = GA(H, cw1t, cb1, MID, nullptr, nullptr, 512, 512, 512, 2048, 1.f, 0.f);
    gemm_bt<128, 128, 2, 2, 0><<<dim3(16, 64, 1), 256, 0, stream>>>(g); }  // pw1 + bias
  glu_kernel<<<4096, 256, 0, stream>>>(MID, GLU);
  dwconv_kernel<<<dim3(32, 16, 8), 256, 0, stream>>>(GLU, dwp, dbp, bn_g, bn_b, bn_m, bn_v, DWO);
  { GemmArgs g = GA(DWO, cw2t, cb2, nullptr, X, nullptr, 1024, 1024, 1024, 512, 1.f, 1.f);
    gemm_bt<128, 128, 2, 2, 2><<<dim3(4, 64, 1), 256, 0, stream>>>(g); }   // x += h@cw2 + b

  // ---- FF2 half-step + post-LN (f32 OUT) ----
  ln_kernel<false><<<8192, 256, 0, stream>>>(X, f2_g, f2_b, H);
  { GemmArgs g = GA(H, f2_w1t, f2_b1, MID, nullptr, nullptr, 512, 512, 512, 2048, 1.f, 0.f);
    gemm_bt<128, 128, 2, 2, 1><<<dim3(16, 64, 1), 256, 0, stream>>>(g); }
  { GemmArgs g = GA(MID, f2_w2t, f2_b2, nullptr, X, nullptr, 2048, 2048, 2048, 512, 1.f, 0.5f);
    gemm_bt<128, 128, 2, 2, 2><<<dim3(4, 64, 1), 256, 0, stream>>>(g); }
  ln_kernel<true><<<8192, 256, 0, stream>>>(X, p_g, p_b, (float*)d_out);
}

// Round 9
// 858.722 us; speedup vs baseline: 1.2939x; 1.2939x over previous
//
#include <hip/hip_runtime.h>
#include <hip/hip_bf16.h>
#include <cstdint>

// Conformer block, MI355X gfx950. f32 inputs, f32 output, bf16 MFMA internals.
// B=8 N=1024 D=512 H=8 DH=64 FF=2048 CI=1024 K=31 MPE=512.
// Round 9: global_load_lds (m97) staging + chunked attention + 64x128 EPI2 tile.

using bf16_t = __hip_bfloat16;
typedef __bf16 bf16x8 __attribute__((ext_vector_type(8)));
typedef float floatx4 __attribute__((ext_vector_type(4)));

struct alignas(16) hbf8 { bf16_t h[8]; };
struct alignas(8)  hbf4 { bf16_t h[4]; };

__device__ __forceinline__ float  b2f(bf16_t h) { return __bfloat162float(h); }
__device__ __forceinline__ bf16_t f2b(float f)  { return __float2bfloat16(f); }
__device__ __forceinline__ float  sig_(float x) { return 1.f / (1.f + __expf(-x)); }

// async global->LDS, 16B/lane; LDS dest must be wave-uniform base + lane*16 (m97 pattern)
__device__ __forceinline__ void async16(const void* g, void* l) {
  __builtin_amdgcn_global_load_lds(
      (const __attribute__((address_space(1))) unsigned int*)(uintptr_t)g,
      (__attribute__((address_space(3))) unsigned int*)(uintptr_t)l, 16, 0, 0);
}

// ---------------------------------------------------------------- GEMM (MFMA)
// C[M,N] = A[M,K] @ Bt[N,K]^T   (bf16 operands, k-contiguous, f32 accum)
// z = blockIdx.z = zb*8+zh (batch, head)
// EPI 0: C_bf16 = alpha*acc + bias     EPI 1: C_bf16 = swish(acc + bias)
// EPI 2: resid_f32 += beta*(acc+bias)  EPI 3: C_bf16 = acc + qr[((zb*1024+i)*8+zh)*ldqr + clip(i-j)+512]
struct GemmArgs {
  const bf16_t* A; const bf16_t* Bt; const float* bias; const bf16_t* qr;
  bf16_t* C; float* resid;
  int K, lda, ldb, ldc, ldqr;
  long sAb, sAh, sBb, sBh, sCb, sCh;
  float alpha, beta;
};

template <int BM, int BN, int WR, int WC, int EPI>
__global__ __launch_bounds__(256) void gemm_bt(GemmArgs g) {
  constexpr int FM = BM / (WR * 16);
  constexpr int FN = BN / (WC * 16);
  constexpr int IA = (BM * 4) / 256;
  constexpr int IB = (BN * 4) / 256;
  __shared__ __align__(16) bf16_t As[BM * 32];
  __shared__ __align__(16) bf16_t Bs[BN * 32];
  const int tid = threadIdx.x;
  const int lane = tid & 63, w = tid >> 6;
  const int bm0 = blockIdx.y * BM, bn0 = blockIdx.x * BN;
  const int zb = blockIdx.z >> 3, zh = blockIdx.z & 7;
  const bf16_t* Ab = g.A + (long)zb * g.sAb + (long)zh * g.sAh;
  const bf16_t* Bb = g.Bt + (long)zb * g.sBb + (long)zh * g.sBh;
  const int wm0 = (w / WC) * (FM * 16);
  const int wn0 = (w % WC) * (FN * 16);
  const int lrow = lane & 15, lq = lane >> 4;

  floatx4 acc[FM][FN] = {};

  for (int k0 = 0; k0 < g.K; k0 += 32) {
#pragma unroll
    for (int i = 0; i < IA; ++i) {
      int c = i * 256 + tid;
      int m = c >> 2, kk = (c & 3) * 8;
      async16(Ab + (long)(bm0 + m) * g.lda + (k0 + kk), (char*)As + c * 16);
    }
#pragma unroll
    for (int i = 0; i < IB; ++i) {
      int c = i * 256 + tid;
      int n = bn0 + (c >> 2), kk = (c & 3) * 8;
      async16(Bb + (long)n * g.ldb + (k0 + kk), (char*)Bs + c * 16);
    }
    __syncthreads();   // drains vmcnt before s_barrier (compiler-inserted)
    bf16x8 af[FM], bfr[FN];
#pragma unroll
    for (int fm = 0; fm < FM; ++fm)
      af[fm] = *(const bf16x8*)(As + (wm0 + fm * 16 + lrow) * 32 + lq * 8);
#pragma unroll
    for (int fn = 0; fn < FN; ++fn)
      bfr[fn] = *(const bf16x8*)(Bs + (wn0 + fn * 16 + lrow) * 32 + lq * 8);
#pragma unroll
    for (int fm = 0; fm < FM; ++fm)
#pragma unroll
      for (int fn = 0; fn < FN; ++fn)
        acc[fm][fn] = __builtin_amdgcn_mfma_f32_16x16x32_bf16(af[fm], bfr[fn], acc[fm][fn], 0, 0, 0);
    __syncthreads();
  }

  const int bi = bm0 + wm0 + lq * 4;    // + fm*16 + r
  const int bj = bn0 + wn0 + lrow;      // + fn*16
  if constexpr (EPI == 2) {
    float* R = g.resid;
#pragma unroll
    for (int fm = 0; fm < FM; ++fm)
#pragma unroll
      for (int fn = 0; fn < FN; ++fn) {
        int j = bj + fn * 16;
        float bv = g.bias ? g.bias[j] : 0.f;
#pragma unroll
        for (int r = 0; r < 4; ++r) {
          long i = bi + fm * 16 + r;
          R[i * g.ldc + j] += g.beta * (acc[fm][fn][r] + bv);
        }
      }
  } else {
    bf16_t* C = g.C + (long)zb * g.sCb + (long)zh * g.sCh;
#pragma unroll
    for (int fm = 0; fm < FM; ++fm)
#pragma unroll
      for (int fn = 0; fn < FN; ++fn) {
        int j = bj + fn * 16;
        float bv = (EPI != 3 && g.bias) ? g.bias[j] : 0.f;
#pragma unroll
        for (int r = 0; r < 4; ++r) {
          int i = bi + fm * 16 + r;
          float v = acc[fm][fn][r];
          if constexpr (EPI == 0) v = g.alpha * v + bv;
          if constexpr (EPI == 1) { v += bv; v = v * sig_(v); }
          if constexpr (EPI == 3) {
            int t = i - j; t = t < -512 ? -512 : (t > 512 ? 512 : t);
            v += b2f(g.qr[(long)((zb * 1024 + i) * 8 + zh) * g.ldqr + (t + 512)]);
          }
          C[(long)i * g.ldc + j] = f2b(v);
        }
      }
  }
}

// ---------------------------------------------------------------- glue kernels
__global__ __launch_bounds__(256) void diag_kernel(float* __restrict__ out, long n, float v) {
  long i = (long)blockIdx.x * 256 + threadIdx.x;
  if (i < n) out[i] = v;
}

__global__ __launch_bounds__(256) void copy_kernel(const float* __restrict__ x, float* __restrict__ X) {
  long idx = ((long)blockIdx.x * 256 + threadIdx.x) * 4;
  *(float4*)(X + idx) = *(const float4*)(x + idx);
}

// pad rel [1025,64] f32 -> RELP [1152,64] bf16 (zero tail)
__global__ __launch_bounds__(256) void relpad_kernel(const float* __restrict__ rel, bf16_t* __restrict__ RELP) {
  int i = blockIdx.x * 256 + threadIdx.x;
  if (i < 73728) {
    int r = i >> 6, c = i & 63;
    RELP[i] = (r < 1025) ? f2b(rel[r * 64 + c]) : f2b(0.f);
  }
}

template <bool F32OUT>
__global__ __launch_bounds__(256) void ln_kernel(const float* __restrict__ X, const float* __restrict__ gam,
                                                 const float* __restrict__ bet, void* __restrict__ outv) {
  int row = blockIdx.x, tid = threadIdx.x;
  const float* x = X + (long)row * 512;
  float a = x[tid], b = x[tid + 256];
  float s = a + b, q = a * a + b * b;
  for (int off = 32; off; off >>= 1) { s += __shfl_down(s, off); q += __shfl_down(q, off); }
  __shared__ float red[8];
  int w = tid >> 6;
  if ((tid & 63) == 0) { red[w] = s; red[w + 4] = q; }
  __syncthreads();
  float ts = red[0] + red[1] + red[2] + red[3];
  float tq = red[4] + red[5] + red[6] + red[7];
  float mean = ts * (1.f / 512.f);
  float var = tq * (1.f / 512.f) - mean * mean;
  float rs = rsqrtf(var + 1e-5f);
  float o0 = (a - mean) * rs * gam[tid]       + bet[tid];
  float o1 = (b - mean) * rs * gam[tid + 256] + bet[tid + 256];
  if constexpr (F32OUT) {
    float* out = (float*)outv;
    out[(long)row * 512 + tid]       = o0;
    out[(long)row * 512 + tid + 256] = o1;
  } else {
    bf16_t* out = (bf16_t*)outv;
    out[(long)row * 512 + tid]       = f2b(o0);
    out[(long)row * 512 + tid + 256] = f2b(o1);
  }
}

__global__ __launch_bounds__(256) void transpose_kernel(const float* __restrict__ in, bf16_t* __restrict__ out,
                                                        int R, int C) {
  __shared__ float t[32][33];
  int c0 = blockIdx.x * 32, r0 = blockIdx.y * 32;
  int tx = threadIdx.x & 31, ty = threadIdx.x >> 5;
#pragma unroll
  for (int i = 0; i < 4; ++i)
    t[ty + i * 8][tx] = in[(long)(r0 + ty + i * 8) * C + c0 + tx];
  __syncthreads();
#pragma unroll
  for (int i = 0; i < 4; ++i)
    out[(long)(c0 + ty + i * 8) * R + r0 + tx] = f2b(t[tx][ty + i * 8]);
}

// VT[z=b*8+h][d][j] = KV[(b*1024+j)*1024 + 512 + h*64 + d]
__global__ __launch_bounds__(256) void vt_kernel(const bf16_t* __restrict__ KV, bf16_t* __restrict__ VT) {
  int jb = blockIdx.x, z = blockIdx.y;
  int b = z >> 3, h = z & 7;
  const bf16_t* src = KV + (long)b * 1024 * 1024 + 512 + h * 64;
  bf16_t* dst = VT + (long)z * 65536;
  __shared__ bf16_t t[64][65];
  int tid = threadIdx.x;
#pragma unroll
  for (int i = 0; i < 16; ++i) {
    int l = i * 256 + tid;
    int j = l >> 6, d = l & 63;
    t[d][j] = src[(long)(jb * 64 + j) * 1024 + d];
  }
  __syncthreads();
#pragma unroll
  for (int i = 0; i < 16; ++i) {
    int l = i * 256 + tid;
    int d = l >> 6, j = l & 63;
    dst[(long)d * 1024 + jb * 64 + j] = t[d][j];
  }
}

__global__ __launch_bounds__(256) void softmax_kernel(bf16_t* __restrict__ S) {
  long row = blockIdx.x;
  bf16_t* p = S + row * 1024;
  int tid = threadIdx.x, w = tid >> 6;
  hbf4 d = *(const hbf4*)(p + tid * 4);
  float v0 = b2f(d.h[0]), v1 = b2f(d.h[1]), v2 = b2f(d.h[2]), v3 = b2f(d.h[3]);
  float m = fmaxf(fmaxf(v0, v1), fmaxf(v2, v3));
  for (int off = 32; off; off >>= 1) m = fmaxf(m, __shfl_down(m, off));
  __shared__ float r1[4], r2[4];
  if ((tid & 63) == 0) r1[w] = m;
  __syncthreads();
  m = fmaxf(fmaxf(r1[0], r1[1]), fmaxf(r1[2], r1[3]));
  float e0 = __expf(v0 - m), e1 = __expf(v1 - m), e2 = __expf(v2 - m), e3 = __expf(v3 - m);
  float s = e0 + e1 + e2 + e3;
  for (int off = 32; off; off >>= 1) s += __shfl_down(s, off);
  if ((tid & 63) == 0) r2[w] = s;
  __syncthreads();
  float inv = 1.f / (r2[0] + r2[1] + r2[2] + r2[3]);
  hbf4 o; o.h[0] = f2b(e0 * inv); o.h[1] = f2b(e1 * inv); o.h[2] = f2b(e2 * inv); o.h[3] = f2b(e3 * inv);
  *(hbf4*)(p + tid * 4) = o;
}

__global__ __launch_bounds__(256) void glu_kernel(const bf16_t* __restrict__ P, bf16_t* __restrict__ out) {
  long idx = ((long)blockIdx.x * 256 + threadIdx.x) * 8;
  long r = idx >> 10;
  int c = (int)(idx & 1023);
  hbf8 a = *(const hbf8*)(P + r * 2048 + c);
  hbf8 g = *(const hbf8*)(P + r * 2048 + 1024 + c);
  hbf8 o;
#pragma unroll
  for (int i = 0; i < 8; ++i) o.h[i] = f2b(b2f(a.h[i]) * sig_(b2f(g.h[i])));
  *(hbf8*)(out + idx) = o;
}

__global__ __launch_bounds__(256) void dwconv_kernel(const bf16_t* __restrict__ G, const float* __restrict__ dw,
    const float* __restrict__ db, const float* __restrict__ bng, const float* __restrict__ bnb,
    const float* __restrict__ bnm, const float* __restrict__ bnv, bf16_t* __restrict__ out) {
  int n0 = blockIdx.x * 32, c0 = blockIdx.y * 64, b = blockIdx.z;
  __shared__ bf16_t t[62][64];
  __shared__ float dws[31][64];
  int tid = threadIdx.x;
  const bf16_t* src = G + (long)b * 1024 * 1024 + c0;
#pragma unroll
  for (int i = 0; i < 16; ++i) {
    int l = i * 256 + tid;
    if (l < 3968) {
      int rr = l >> 6, c = l & 63;
      int n = n0 - 15 + rr;
      t[rr][c] = (n >= 0 && n < 1024) ? src[(long)n * 1024 + c] : f2b(0.f);
    }
  }
#pragma unroll
  for (int i = 0; i < 8; ++i) {
    int l = i * 256 + tid;
    if (l < 1984) {
      int k = l >> 6, c = l & 63;
      dws[k][c] = dw[(long)(c0 + c) * 31 + k];
    }
  }
  __syncthreads();
  int c = tid & 63, nl = tid >> 6;
  float rs = rsqrtf(bnv[c0 + c] + 1e-5f);
  float sc = rs * bng[c0 + c];
  float ab = (db[c0 + c] - bnm[c0 + c]) * sc + bnb[c0 + c];
#pragma unroll
  for (int j = 0; j < 8; ++j) {
    int rr = nl * 8 + j;
    float s = 0.f;
#pragma unroll
    for (int k = 0; k < 31; ++k) s += b2f(t[rr + k][c]) * dws[k][c];
    float y = s * sc + ab;
    out[((long)b * 1024 + n0 + rr) * 1024 + c0 + c] = f2b(y * sig_(y));
  }
}

// ---------------------------------------------------------------- launch
extern "C" void kernel_launch(void* const* d_in, const int* in_sizes, int n_in,
                              void* d_out, int out_size, void* d_ws, size_t ws_size,
                              hipStream_t stream) {
  auto fail = [&](float code) {
    diag_kernel<<<(out_size + 255) / 256, 256, 0, stream>>>((float*)d_out, out_size, code);
  };
  if (n_in != 34)             { fail(70.f);  return; }
  if (in_sizes[0] != 4194304) { fail(80.f);  return; }

  const float* x     = (const float*)d_in[0];
  const float* f1_g  = (const float*)d_in[1];
  const float* f1_b  = (const float*)d_in[2];
  const float* f1_w1 = (const float*)d_in[3];
  const float* f1_b1 = (const float*)d_in[4];
  const float* f1_w2 = (const float*)d_in[5];
  const float* f1_b2 = (const float*)d_in[6];
  const float* a_g   = (const float*)d_in[7];
  const float* a_b   = (const float*)d_in[8];
  const float* wq    = (const float*)d_in[9];
  const float* wkv   = (const float*)d_in[10];
  const float* wo    = (const float*)d_in[11];
  const float* wo_b  = (const float*)d_in[12];
  const float* rel   = (const float*)d_in[13];
  const float* c_g   = (const float*)d_in[14];
  const float* c_b   = (const float*)d_in[15];
  const float* cw1   = (const float*)d_in[16];
  const float* cb1   = (const float*)d_in[17];
  const float* dwp   = (const float*)d_in[18];
  const float* dbp   = (const float*)d_in[19];
  const float* bn_g  = (const float*)d_in[20];
  const float* bn_b  = (const float*)d_in[21];
  const float* bn_m  = (const float*)d_in[22];
  const float* bn_v  = (const float*)d_in[23];
  const float* cw2   = (const float*)d_in[24];
  const float* cb2   = (const float*)d_in[25];
  const float* f2_g  = (const float*)d_in[26];
  const float* f2_b  = (const float*)d_in[27];
  const float* f2_w1 = (const float*)d_in[28];
  const float* f2_b1 = (const float*)d_in[29];
  const float* f2_w2 = (const float*)d_in[30];
  const float* f2_b2 = (const float*)d_in[31];
  const float* p_g   = (const float*)d_in[32];
  const float* p_b   = (const float*)d_in[33];

  // ---- workspace arena ----
  // X 16.78M | WT 13.63M | D 33.55M {Q,KV,VT}/{GLU,DWO} | E: {MID 33.55M} vs
  // attention chunk {QR NB*18.87M, S NB*16.78M} | RELP after max(...)
  char* ws = (char*)d_ws;
  const size_t OFF_X  = 0;
  const size_t OFF_WT = 16777216;
  const size_t OFF_D  = 30408704;
  const size_t OFF_E  = 63963136;
  // chunk size: largest NB whose QR+S fits alongside the rest
  int NB = 1;
  {
    const int cands[3] = {8, 4, 2};
    for (int ci = 0; ci < 3; ++ci) {
      int nb = cands[ci];
      unsigned long long attn = (unsigned long long)nb * 35651584ULL;
      unsigned long long emax = attn > 33554432ULL ? attn : 33554432ULL;
      if (ws_size >= OFF_E + emax + 147456ULL) { NB = nb; break; }
    }
  }
  {
    unsigned long long attn = (unsigned long long)NB * 35651584ULL;
    unsigned long long emax = attn > 33554432ULL ? attn : 33554432ULL;
    if (ws_size < OFF_E + emax + 147456ULL) { fail(200.f); return; }
  }
  size_t relp_off;
  {
    unsigned long long attn = (unsigned long long)NB * 35651584ULL;
    unsigned long long emax = attn > 33554432ULL ? attn : 33554432ULL;
    relp_off = OFF_E + (size_t)emax;
  }

  float*  X   = (float*)(ws + OFF_X);
  bf16_t* WT  = (bf16_t*)(ws + OFF_WT);
  bf16_t* Q   = (bf16_t*)(ws + OFF_D);
  bf16_t* KV  = (bf16_t*)(ws + OFF_D + 8388608);
  bf16_t* VT  = (bf16_t*)(ws + OFF_D + 25165824);
  bf16_t* GLU = (bf16_t*)(ws + OFF_D);
  bf16_t* DWO = (bf16_t*)(ws + OFF_D + 16777216);
  bf16_t* MID = (bf16_t*)(ws + OFF_E);
  bf16_t* QR  = (bf16_t*)(ws + OFF_E);                              // chunk-local
  bf16_t* S   = (bf16_t*)(ws + OFF_E + (size_t)NB * 18874368);      // chunk-local
  bf16_t* RELP= (bf16_t*)(ws + relp_off);
  bf16_t* H   = (bf16_t*)d_out;   // bf16 scratch inside f32 out buffer
  bf16_t* O   = (bf16_t*)d_out;   // final f32 LN overwrites at the end

  bf16_t* f1_w1t = WT;            bf16_t* f1_w2t = WT + 1048576;
  bf16_t* wqt    = WT + 2097152;  bf16_t* wkvt   = WT + 2359296;
  bf16_t* wot    = WT + 2883584;  bf16_t* cw1t   = WT + 3145728;
  bf16_t* cw2t   = WT + 4194304;  bf16_t* f2_w1t = WT + 4718592;
  bf16_t* f2_w2t = WT + 5767168;

  auto GA = [](const bf16_t* A, const bf16_t* Bt, const float* bias, bf16_t* C,
               float* resid, const bf16_t* qr, int K, int lda, int ldb, int ldc,
               float alpha, float beta) {
    GemmArgs g{}; g.A = A; g.Bt = Bt; g.bias = bias; g.qr = qr; g.C = C; g.resid = resid;
    g.K = K; g.lda = lda; g.ldb = ldb; g.ldc = ldc; g.ldqr = 1152;
    g.sAb = g.sAh = g.sBb = g.sBh = g.sCb = g.sCh = 0; g.alpha = alpha; g.beta = beta;
    return g;
  };
  auto T = [&](const float* in, bf16_t* out, int R, int C) {
    transpose_kernel<<<dim3(C / 32, R / 32), 256, 0, stream>>>(in, out, R, C);
  };

  copy_kernel<<<4096, 256, 0, stream>>>(x, X);
  relpad_kernel<<<288, 256, 0, stream>>>(rel, RELP);
  T(f1_w1, f1_w1t, 512, 2048);  T(f1_w2, f1_w2t, 2048, 512);
  T(wq, wqt, 512, 512);         T(wkv, wkvt, 512, 1024);
  T(wo, wot, 512, 512);         T(cw1, cw1t, 512, 2048);
  T(cw2, cw2t, 1024, 512);      T(f2_w1, f2_w1t, 512, 2048);
  T(f2_w2, f2_w2t, 2048, 512);

  // ---- FF1 half-step ----
  ln_kernel<false><<<8192, 256, 0, stream>>>(X, f1_g, f1_b, H);
  { GemmArgs g = GA(H, f1_w1t, f1_b1, MID, nullptr, nullptr, 512, 512, 512, 2048, 1.f, 0.f);
    gemm_bt<128, 128, 2, 2, 1><<<dim3(16, 64, 1), 256, 0, stream>>>(g); }
  { GemmArgs g = GA(MID, f1_w2t, f1_b2, nullptr, X, nullptr, 2048, 2048, 2048, 512, 1.f, 0.5f);
    gemm_bt<64, 128, 1, 4, 2><<<dim3(4, 128, 1), 256, 0, stream>>>(g); }

  // ---- attention ----
  ln_kernel<false><<<8192, 256, 0, stream>>>(X, a_g, a_b, H);
  { GemmArgs g = GA(H, wqt, nullptr, Q, nullptr, nullptr, 512, 512, 512, 512, 0.125f, 0.f);
    gemm_bt<128, 128, 2, 2, 0><<<dim3(4, 64, 1), 256, 0, stream>>>(g); }   // q (scale folded)
  { GemmArgs g = GA(H, wkvt, nullptr, KV, nullptr, nullptr, 512, 512, 512, 1024, 1.f, 0.f);
    gemm_bt<128, 128, 2, 2, 0><<<dim3(8, 64, 1), 256, 0, stream>>>(g); }   // k|v
  vt_kernel<<<dim3(16, 64), 256, 0, stream>>>(KV, VT);

  for (int b0 = 0; b0 < 8; b0 += NB) {
    const bf16_t* Qc  = Q  + (long)b0 * 524288;
    const bf16_t* KVc = KV + (long)b0 * 1048576;
    // qr = q @ RELP^T for whole chunk: Q viewed as [NB*8192, 64] flat rows
    { GemmArgs g = GA(Qc, RELP, nullptr, QR, nullptr, nullptr, 64, 64, 64, 1152, 1.f, 0.f);
      gemm_bt<128, 128, 2, 2, 0><<<dim3(9, NB * 64, 1), 256, 0, stream>>>(g); }
    // S[zb,zh,i,j] = q.k^T + rel bias, z = zb*8+zh
    { GemmArgs g = GA(Qc, KVc, nullptr, S, nullptr, QR, 64, 512, 1024, 1024, 1.f, 0.f);
      g.sAb = 524288; g.sAh = 64; g.sBb = 1048576; g.sBh = 64;
      g.sCb = 8388608; g.sCh = 1048576;
      gemm_bt<128, 128, 2, 2, 3><<<dim3(8, 8, NB * 8), 256, 0, stream>>>(g); }
    softmax_kernel<<<NB * 8192, 256, 0, stream>>>(S);
    // O = P @ V
    { GemmArgs g = GA(S, VT + (long)b0 * 524288, nullptr, O + (long)b0 * 524288,
                      nullptr, nullptr, 1024, 1024, 1024, 512, 1.f, 0.f);
      g.sAb = 8388608; g.sAh = 1048576; g.sBb = 524288; g.sBh = 65536;
      g.sCb = 524288; g.sCh = 64;
      gemm_bt<128, 64, 4, 1, 0><<<dim3(1, 8, NB * 8), 256, 0, stream>>>(g); }
  }
  { GemmArgs g = GA(O, wot, wo_b, nullptr, X, nullptr, 512, 512, 512, 512, 1.f, 1.f);
    gemm_bt<64, 128, 1, 4, 2><<<dim3(4, 128, 1), 256, 0, stream>>>(g); }   // x += o@wo + b

  // ---- conv module ----
  ln_kernel<false><<<8192, 256, 0, stream>>>(X, c_g, c_b, H);
  { GemmArgs g = GA(H, cw1t, cb1, MID, nullptr, nullptr, 512, 512, 512, 2048, 1.f, 0.f);
    gemm_bt<128, 128, 2, 2, 0><<<dim3(16, 64, 1), 256, 0, stream>>>(g); }  // pw1 + bias
  glu_kernel<<<4096, 256, 0, stream>>>(MID, GLU);
  dwconv_kernel<<<dim3(32, 16, 8), 256, 0, stream>>>(GLU, dwp, dbp, bn_g, bn_b, bn_m, bn_v, DWO);
  { GemmArgs g = GA(DWO, cw2t, cb2, nullptr, X, nullptr, 1024, 1024, 1024, 512, 1.f, 1.f);
    gemm_bt<64, 128, 1, 4, 2><<<dim3(4, 128, 1), 256, 0, stream>>>(g); }   // x += h@cw2 + b

  // ---- FF2 half-step + post-LN (f32 out) ----
  ln_kernel<false><<<8192, 256, 0, stream>>>(X, f2_g, f2_b, H);
  { GemmArgs g = GA(H, f2_w1t, f2_b1, MID, nullptr, nullptr, 512, 512, 512, 2048, 1.f, 0.f);
    gemm_bt<128, 128, 2, 2, 1><<<dim3(16, 64, 1), 256, 0, stream>>>(g); }
  { GemmArgs g = GA(MID, f2_w2t, f2_b2, nullptr, X, nullptr, 2048, 2048, 2048, 512, 1.f, 0.5f);
    gemm_bt<64, 128, 1, 4, 2><<<dim3(4, 128, 1), 256, 0, stream>>>(g); }
  ln_kernel<true><<<8192, 256, 0, stream>>>(X, p_g, p_b, (float*)d_out);
}